// Round 9
// baseline (216.102 us; speedup 1.0000x reference)
//
#include <hip/hip_runtime.h>
#include <stdint.h>

#define V      768
#define FINC   32
#define FOUTC  32
#define XYZ    512
#define NB     2
#define ROWP   40      // bf16 CUR row stride in ushorts (80 B)
#define QROW   48      // fp8 CURQ row stride in bytes (3*16: slot (3r+j)&7 covers all 8)
#define MAXDEG 32
#define EROWS  (MAXDEG + 2)   // transposed-ELL rows incl. prefetch pad

typedef unsigned short u16;
typedef unsigned int   u32;
typedef short bf16x8 __attribute__((ext_vector_type(8)));
typedef float f32x4  __attribute__((ext_vector_type(4)));
typedef float f32x2  __attribute__((ext_vector_type(2)));

__device__ __forceinline__ u16 f2bf(float f) {
  u32 u = __float_as_uint(f);
  u32 r = u + 0x7fffu + ((u >> 16) & 1u);   // RNE
  return (u16)(r >> 16);
}
__device__ __forceinline__ float bflo(u32 w) { return __uint_as_float(w << 16); }
__device__ __forceinline__ float bfhi(u32 w) { return __uint_as_float(w & 0xffff0000u); }
__device__ __forceinline__ u32 cvtpk_bf16(float lo, float hi) {
  u32 r;
  asm("v_cvt_pk_bf16_f32 %0, %1, %2" : "=v"(r) : "v"(lo), "v"(hi));
  return r;
}

// ---------- kernel 1: deterministic ELL build, interleaved (col,val), zero-padded ----------
__global__ __launch_bounds__(64) void build_ell(const int* __restrict__ rows,
                                                const int* __restrict__ cols,
                                                const float* __restrict__ vals,
                                                int nnz,
                                                int2* __restrict__ epair,
                                                int* __restrict__ deg) {
  int v = blockIdx.x;
  int lane = threadIdx.x;
  int cnt = 0;
  for (int base = 0; base < nnz; base += 64) {
    int i = base + lane;
    bool m = (i < nnz) && (rows[i] == v);
    unsigned long long mask = __ballot(m);
    if (m) {
      int pos = cnt + __popcll(mask & ((1ull << lane) - 1ull));
      if (pos < MAXDEG)
        epair[v * MAXDEG + pos] = make_int2(cols[i], __float_as_int(vals[i]));
    }
    cnt += __popcll(mask);
  }
  int d = cnt < MAXDEG ? cnt : MAXDEG;
  for (int p = d + lane; p < MAXDEG; p += 64)
    epair[v * MAXDEG + p] = make_int2(0, 0);
  if (lane == 0) deg[v] = d;
}

// ---------- kernel 2: degree sort + SIMD-balanced placement + TRANSPOSED ELL ----------
__global__ __launch_bounds__(V) void sort_rows(const int2* __restrict__ epair,
                                               const int* __restrict__ deg,
                                               int2* __restrict__ ep3,     // [EROWS][V]
                                               int* __restrict__ perm,
                                               int* __restrict__ inv_g,
                                               int* __restrict__ wtrip) {
  __shared__ int sdeg[V];
  __shared__ u16 sinv[V];
  int v = threadIdx.x;
  int d = deg[v];
  sdeg[v] = d;
  __syncthreads();
  int r = 0;                       // rank (desc degree, tie v asc)
  for (int u = 0; u < V; ++u) {
    int du = sdeg[u];
    r += (du > d) || (du == d && u < v);
  }
  // group gr=r>>6 -> wave GINV[gr]; nibble-packed GINV = {0,1,2,3,7,11,6,10,5,9,4,8}
  const unsigned long long GPK = 0x8495A6B73210ull;
  int w = (int)((GPK >> (4 * (r >> 6))) & 15ull);
  int p = w * 64 + (r & 63);
  perm[p] = v;
  inv_g[v] = p;
  sinv[v] = (u16)p;
  if ((r & 63) == 0) wtrip[w] = d;
  __syncthreads();
  for (int e = 0; e < EROWS; ++e) {
    int2 o = make_int2(0, 0);
    if (e < d) {
      int2 pe = epair[v * MAXDEG + e];
      o = make_int2((int)sinv[pe.x] * QROW, pe.y);   // fp8 CURQ byte offset
    }
    ep3[e * V + p] = o;
  }
}

// ---------- kernel 3: x [B,Fin,V,XYZ] f32 -> xT [B,XYZ,pv,Fin] bf16 ----------
// LDS-tiled, both sides coalesced.
#define TXV 12
__global__ __launch_bounds__(512) void transpose_x(const float* __restrict__ x,
                                                   const int* __restrict__ perm,
                                                   u16* __restrict__ xT) {
  __shared__ u16 TL[384][66];   // [pair=(vloc,f)][xyz], 50688 B, conflict-free
  __shared__ int PV[TXV];
  int g = blockIdx.x;           // b(2) x pvt(64) x xt(8)
  int b = g >> 9, pvt = (g >> 3) & 63, xt = g & 7;
  int pv0 = pvt * TXV;
  int xyz0 = xt * 64;
  int t = threadIdx.x;
  if (t < TXV) PV[t] = perm[pv0 + t];
  __syncthreads();
  int lane = t & 63, pg = t >> 6;   // 8 pair-groups
#pragma unroll
  for (int st = 0; st < 48; ++st) {
    int pair = st * 8 + pg;         // 0..383
    int vloc = pair >> 5, f = pair & 31;
    float val = x[((size_t)(b * FINC + f) * V + PV[vloc]) * XYZ + xyz0 + lane];
    TL[pair][lane] = f2bf(val);
  }
  __syncthreads();
  int s = t & 7, xyz = t >> 3;
  u32* dst = (u32*)(xT + ((size_t)(b * XYZ + xyz0 + xyz) * V + pv0) * FINC);
#pragma unroll
  for (int it = 0; it < 24; ++it) {
    int i = s + 8 * it;             // u32 index 0..191
    u32 lo = TL[2 * i][xyz], hi = TL[2 * i + 1][xyz];
    dst[i] = lo | (hi << 16);
  }
}

// ---------- kernel 4: fused recursion + MFMA GEMM; fp8 gather path ----------
__global__ __launch_bounds__(1024, 4) void cheb_main(
    const u16* __restrict__ xT, const int2* __restrict__ ep3,
    const int* __restrict__ perm, const int* __restrict__ wtrip,
    const float* __restrict__ weight, const float* __restrict__ bias,
    u32* __restrict__ stage) {
  __shared__ __align__(16) u16   CUR[V * ROWP];        // 61440 B (bf16, GEMM A)
  __shared__ __align__(16) unsigned char CURQ[V * QROW]; // 36864 B (fp8, gather)
  __shared__ __align__(16) uint4 WF[5][2][64];         // 10240 B
  __shared__ u16 PRM[V];
  __shared__ int WT[12];

  int g = blockIdx.x;
  int xcd = g & 7;
  int u = g >> 3;
  int phase = u >> 5;
  int xyz = xcd * 32 + (u & 31) + (phase & 1) * 256;
  int b = phase >> 1;
  int slice = b * XYZ + xyz;

  int tid = threadIdx.x;
  int lane = tid & 63;
  int w = tid >> 6;               // wave 0..15
  int l15 = lane & 15, l4 = lane >> 4;
  bool gath = tid < V;            // waves 0..11 gather/own rows

  if (tid < 640) {
    int k = tid >> 7, n = (tid >> 6) & 1, ln = tid & 63;
    int a15 = ln & 15, a4 = ln >> 4;
    u32 pw[4];
#pragma unroll
    for (int p = 0; p < 4; ++p) {
      float w0 = weight[(size_t)(k * FINC + a4 * 8 + 2 * p) * FOUTC + n * 16 + a15];
      float w1 = weight[(size_t)(k * FINC + a4 * 8 + 2 * p + 1) * FOUTC + n * 16 + a15];
      pw[p] = (u32)f2bf(w0) | ((u32)f2bf(w1) << 16);
    }
    WF[k][n][ln] = make_uint4(pw[0], pw[1], pw[2], pw[3]);
  }
  if (tid < 12) WT[tid] = wtrip[tid];
  if (gath) PRM[tid] = (u16)perm[tid];
  float bsv[2] = {bias[l15], bias[16 + l15]};

  // ---- load permuted slice row tid into LDS (bf16 + fp8 shadow), keep packed regs
  u32 curpk[16], prevpk[16];
  if (gath) {
    const uint4* src = (const uint4*)(xT + (size_t)slice * V * FINC) + tid * 4;
    uint4* dst = (uint4*)(CUR + tid * ROWP);
    u32 q8[8];
#pragma unroll
    for (int j = 0; j < 4; ++j) {
      uint4 q = src[j];
      dst[j] = q;
      curpk[4 * j] = q.x; curpk[4 * j + 1] = q.y;
      curpk[4 * j + 2] = q.z; curpk[4 * j + 3] = q.w;
    }
#pragma unroll
    for (int d = 0; d < 8; ++d) {
      u32 p0 = curpk[2 * d], p1 = curpk[2 * d + 1];
      u32 q = __builtin_amdgcn_cvt_pk_fp8_f32(bflo(p0), bfhi(p0), 0, false);
      q8[d] = __builtin_amdgcn_cvt_pk_fp8_f32(bflo(p1), bfhi(p1), q, true);
    }
    uint4* qp = (uint4*)(CURQ + tid * QROW);
    qp[0] = make_uint4(q8[0], q8[1], q8[2], q8[3]);
    qp[1] = make_uint4(q8[4], q8[5], q8[6], q8[7]);
  }
  __syncthreads();   // orders all xT reads before aliased stage writes at the end

  int trip = 0;
  if (w < 12) trip = __builtin_amdgcn_readfirstlane(WT[w]);
  const int2* pp = ep3 + tid;

  f32x4 acc[3][2];
#pragma unroll
  for (int a = 0; a < 3; ++a)
#pragma unroll
    for (int n = 0; n < 2; ++n) acc[a][n] = (f32x4){0.f, 0.f, 0.f, 0.f};

  // 16 waves x 48 rows each
  auto gemm_acc = [&](int k) {
    bf16x8 bn0 = *(const bf16x8*)&WF[k][0][lane];
    bf16x8 bn1 = *(const bf16x8*)&WF[k][1][lane];
#pragma unroll
    for (int a = 0; a < 3; ++a) {
      int row = w * 48 + a * 16 + l15;
      bf16x8 af = *(const bf16x8*)(CUR + row * ROWP + l4 * 8);
      acc[a][0] = __builtin_amdgcn_mfma_f32_16x16x32_bf16(af, bn0, acc[a][0], 0, 0, 0);
      acc[a][1] = __builtin_amdgcn_mfma_f32_16x16x32_bf16(af, bn1, acc[a][1], 0, 0, 0);
    }
  };

  // fa2 = (L * CUR)[tid,:] — fp8 rows: 2 ds_read_b128/edge + HW cvt unpack
  f32x2 fa2[16];
  auto gather = [&]() {
#pragma unroll
    for (int j = 0; j < 16; ++j) fa2[j] = (f32x2){0.f, 0.f};
    int2 pe0 = pp[0];
    int2 pe1 = pp[V];
    for (int e = 0; e < trip; ++e) {
      int2 nx = pp[(e + 2) * V];
      float fv = __int_as_float(pe0.y);
      f32x2 fv2 = {fv, fv};
      const uint4* sp = (const uint4*)(CURQ + (u32)pe0.x);
      uint4 qa = sp[0], qb = sp[1];
      u32 wq[8] = {qa.x, qa.y, qa.z, qa.w, qb.x, qb.y, qb.z, qb.w};
#pragma unroll
      for (int d = 0; d < 8; ++d) {
        f32x2 s0 = __builtin_amdgcn_cvt_pk_f32_fp8(wq[d], false);
        f32x2 s1 = __builtin_amdgcn_cvt_pk_f32_fp8(wq[d], true);
        fa2[2 * d]     += fv2 * s0;
        fa2[2 * d + 1] += fv2 * s1;
      }
      pe0 = pe1; pe1 = nx;
    }
  };

  auto store_cur = [&](const u32* q8) {
    uint4* dp = (uint4*)(CUR + tid * ROWP);
#pragma unroll
    for (int j = 0; j < 4; ++j)
      dp[j] = make_uint4(curpk[4 * j], curpk[4 * j + 1], curpk[4 * j + 2], curpk[4 * j + 3]);
    uint4* qp = (uint4*)(CURQ + tid * QROW);
    qp[0] = make_uint4(q8[0], q8[1], q8[2], q8[3]);
    qp[1] = make_uint4(q8[4], q8[5], q8[6], q8[7]);
  };

  // ---- phase 0: T0 resident; T1 = L*T0
  gemm_acc(0);
  if (gath) gather();
  __syncthreads();
  if (gath) {
    u32 q8[8];
#pragma unroll
    for (int j = 0; j < 16; ++j) {
      prevpk[j] = curpk[j];
      float t0 = fa2[j][0], t1 = fa2[j][1];
      curpk[j] = cvtpk_bf16(t0, t1);
      if ((j & 1) == 0) q8[j >> 1] = __builtin_amdgcn_cvt_pk_fp8_f32(t0, t1, 0, false);
      else              q8[j >> 1] = __builtin_amdgcn_cvt_pk_fp8_f32(t0, t1, q8[j >> 1], true);
    }
    store_cur(q8);
  }
  __syncthreads();

  // ---- phases 1..3: T_{k+1} = 2*L*T_k - T_{k-1}
#pragma unroll
  for (int ph = 1; ph <= 3; ++ph) {
    gemm_acc(ph);
    if (gath) gather();
    __syncthreads();
    if (gath) {
      u32 q8[8];
#pragma unroll
      for (int j = 0; j < 16; ++j) {
        u32 pv = prevpk[j];
        float t0 = 2.f * fa2[j][0] - bflo(pv);
        float t1 = 2.f * fa2[j][1] - bfhi(pv);
        prevpk[j] = curpk[j];
        curpk[j] = cvtpk_bf16(t0, t1);
        if ((j & 1) == 0) q8[j >> 1] = __builtin_amdgcn_cvt_pk_fp8_f32(t0, t1, 0, false);
        else              q8[j >> 1] = __builtin_amdgcn_cvt_pk_fp8_f32(t0, t1, q8[j >> 1], true);
      }
      store_cur(q8);
    }
    __syncthreads();
  }

  // ---- phase 4
  gemm_acc(4);

  // ---- epilogue: pack (fout, fout+16) per lane -> bf16 stage[slice][v][l15]
  u32* stg = stage + (size_t)slice * (V * 16);
#pragma unroll
  for (int a = 0; a < 3; ++a) {
#pragma unroll
    for (int r = 0; r < 4; ++r) {
      int vr = PRM[w * 48 + a * 16 + l4 * 4 + r];
      u32 pk = cvtpk_bf16(acc[a][0][r] + bsv[0], acc[a][1][r] + bsv[1]);
      stg[vr * 16 + l15] = pk;
    }
  }
}

// ---------- kernel 5: stage [b][xyz][v][f2] bf16 -> out [b][fout][v][xyz] f32 ----------
#define TO_VT  12
#define TO_PAD 193
__global__ __launch_bounds__(512) void transpose_out(const u32* __restrict__ stage,
                                                     float* __restrict__ out) {
  __shared__ u32 T[64 * TO_PAD];   // 49.4 KB -> 2 blocks/CU
  int g = blockIdx.x;              // b(2) x vt(64) x xt(8)
  int b = g >> 9, vt = (g >> 3) & 63, xt = g & 7;
  int v0 = vt * TO_VT;
  int xyz0 = xt * 64;
  int t = threadIdx.x;
  const u32* base = stage + (size_t)(b * XYZ + xyz0) * (V * 16) + v0 * 16;
#pragma unroll
  for (int i = 0; i < 6; ++i) {
    int idx4 = i * 512 + t;
    int j = idx4 / 48;
    int c4 = idx4 - j * 48;
    uint4 q = *(const uint4*)(base + (size_t)j * (V * 16) + c4 * 4);
    int w0 = c4 * 4;
    T[j * TO_PAD + w0]     = q.x;
    T[j * TO_PAD + w0 + 1] = q.y;
    T[j * TO_PAD + w0 + 2] = q.z;
    T[j * TO_PAD + w0 + 3] = q.w;
  }
  __syncthreads();
  int wv = t >> 6, lane = t & 63;  // wave, lane=xyz
#pragma unroll
  for (int i = 0; i < 48; ++i) {
    int fout = wv * 4 + i / 12;
    int vv = i % 12;
    u32 pk = T[lane * TO_PAD + vv * 16 + (fout & 15)];
    float val = (fout < 16) ? bflo(pk) : bfhi(pk);
    out[((size_t)(b * FOUTC + fout) * V + v0 + vv) * XYZ + xyz0 + lane] = val;
  }
}

extern "C" void kernel_launch(void* const* d_in, const int* in_sizes, int n_in,
                              void* d_out, int out_size, void* d_ws, size_t ws_size,
                              hipStream_t stream) {
  const int*   lap_rows = (const int*)d_in[0];
  const int*   lap_cols = (const int*)d_in[1];
  const float* lap_vals = (const float*)d_in[2];
  const float* x        = (const float*)d_in[3];
  const float* weight   = (const float*)d_in[4];
  const float* bias     = (const float*)d_in[5];
  float* out = (float*)d_out;
  int nnz = in_sizes[0];

  char* ws = (char*)d_ws;
  const size_t XT_BYTES = (size_t)NB * XYZ * V * FINC * sizeof(u16);  // 50,331,648
  const size_t EP_BYTES = (size_t)V * MAXDEG * 8;                     // 196,608
  const size_t E3_BYTES = (size_t)EROWS * V * 8;                      // 208,896
  u16*  xT    = (u16*)ws;                // aliased: bf16 stage [b][xyz][v][f2]
  u32*  stg   = (u32*)ws;
  int2* epair = (int2*)(ws + XT_BYTES);
  int2* ep3   = (int2*)(ws + XT_BYTES + EP_BYTES);
  int*  deg   = (int*)(ws + XT_BYTES + EP_BYTES + E3_BYTES);
  int*  perm  = (int*)(ws + XT_BYTES + EP_BYTES + E3_BYTES + 3072);
  int*  inv_g = (int*)(ws + XT_BYTES + EP_BYTES + E3_BYTES + 6144);
  int*  wtrip = (int*)(ws + XT_BYTES + EP_BYTES + E3_BYTES + 9216);

  hipLaunchKernelGGL(build_ell, dim3(V), dim3(64), 0, stream,
                     lap_rows, lap_cols, lap_vals, nnz, epair, deg);
  hipLaunchKernelGGL(sort_rows, dim3(1), dim3(V), 0, stream,
                     epair, deg, ep3, perm, inv_g, wtrip);
  hipLaunchKernelGGL(transpose_x, dim3(NB * 64 * 8), dim3(512), 0, stream,
                     x, perm, xT);
  hipLaunchKernelGGL(cheb_main, dim3(NB * XYZ), dim3(1024), 0, stream,
                     xT, ep3, perm, wtrip, weight, bias, stg);
  hipLaunchKernelGGL(transpose_out, dim3(NB * 64 * 8), dim3(512), 0, stream,
                     stg, out);
}

// Round 10
// 204.648 us; speedup vs baseline: 1.0560x; 1.0560x over previous
//
#include <hip/hip_runtime.h>
#include <stdint.h>

#define V      768
#define FINC   32
#define FOUTC  32
#define XYZ    512
#define NB     2
#define ROWP   40      // bf16 LDS row stride in ushorts (80 B)
#define MAXDEG 32
#define EROWS  36      // transposed-ELL rows incl. 4-deep prefetch pad

typedef unsigned short u16;
typedef unsigned int   u32;
typedef short bf16x8 __attribute__((ext_vector_type(8)));
typedef float f32x4  __attribute__((ext_vector_type(4)));
typedef float f32x2  __attribute__((ext_vector_type(2)));

__device__ __forceinline__ u16 f2bf(float f) {
  u32 u = __float_as_uint(f);
  u32 r = u + 0x7fffu + ((u >> 16) & 1u);   // RNE
  return (u16)(r >> 16);
}
__device__ __forceinline__ float bflo(u32 w) { return __uint_as_float(w << 16); }
__device__ __forceinline__ float bfhi(u32 w) { return __uint_as_float(w & 0xffff0000u); }
// hi bf16 with low-16 mantissa garbage: <=2^-8 relative error, saves the AND
__device__ __forceinline__ float bfhi_raw(u32 w) { return __uint_as_float(w); }
__device__ __forceinline__ u32 cvtpk_bf16(float lo, float hi) {
  u32 r;
  asm("v_cvt_pk_bf16_f32 %0, %1, %2" : "=v"(r) : "v"(lo), "v"(hi));
  return r;
}

// ---------- kernel 1: deterministic ELL build, interleaved (col,val), zero-padded ----------
__global__ __launch_bounds__(64) void build_ell(const int* __restrict__ rows,
                                                const int* __restrict__ cols,
                                                const float* __restrict__ vals,
                                                int nnz,
                                                int2* __restrict__ epair,
                                                int* __restrict__ deg) {
  int v = blockIdx.x;
  int lane = threadIdx.x;
  int cnt = 0;
  for (int base = 0; base < nnz; base += 64) {
    int i = base + lane;
    bool m = (i < nnz) && (rows[i] == v);
    unsigned long long mask = __ballot(m);
    if (m) {
      int pos = cnt + __popcll(mask & ((1ull << lane) - 1ull));
      if (pos < MAXDEG)
        epair[v * MAXDEG + pos] = make_int2(cols[i], __float_as_int(vals[i]));
    }
    cnt += __popcll(mask);
  }
  int d = cnt < MAXDEG ? cnt : MAXDEG;
  for (int p = d + lane; p < MAXDEG; p += 64)
    epair[v * MAXDEG + p] = make_int2(0, 0);
  if (lane == 0) deg[v] = d;
}

// ---------- kernel 2: degree sort + SIMD-balanced placement + TRANSPOSED ELL ----------
__global__ __launch_bounds__(V) void sort_rows(const int2* __restrict__ epair,
                                               const int* __restrict__ deg,
                                               int2* __restrict__ ep3,     // [EROWS][V]
                                               int* __restrict__ perm,
                                               int* __restrict__ inv_g,
                                               int* __restrict__ wtrip) {
  __shared__ int sdeg[V];
  __shared__ u16 sinv[V];
  int v = threadIdx.x;
  int d = deg[v];
  sdeg[v] = d;
  __syncthreads();
  int r = 0;                       // rank (desc degree, tie v asc)
  for (int u = 0; u < V; ++u) {
    int du = sdeg[u];
    r += (du > d) || (du == d && u < v);
  }
  // group gr=r>>6 -> wave GINV[gr]; nibble-packed GINV = {0,1,2,3,7,11,6,10,5,9,4,8}
  const unsigned long long GPK = 0x8495A6B73210ull;
  int w = (int)((GPK >> (4 * (r >> 6))) & 15ull);
  int p = w * 64 + (r & 63);
  perm[p] = v;
  inv_g[v] = p;
  sinv[v] = (u16)p;
  if ((r & 63) == 0) wtrip[w] = d;
  __syncthreads();
  for (int e = 0; e < EROWS; ++e) {
    int2 o = make_int2(0, 0);
    if (e < d) {
      int2 pe = epair[v * MAXDEG + e];
      o = make_int2((int)sinv[pe.x] * (ROWP * 2), pe.y);   // bf16 CUR byte offset
    }
    ep3[e * V + p] = o;
  }
}

// ---------- kernel 3: x [B,Fin,V,XYZ] f32 -> xT [B,XYZ,pv,Fin] bf16 ----------
#define TXV 12
__global__ __launch_bounds__(512) void transpose_x(const float* __restrict__ x,
                                                   const int* __restrict__ perm,
                                                   u16* __restrict__ xT) {
  __shared__ u16 TL[384][66];   // [pair=(vloc,f)][xyz], 50688 B, conflict-free
  __shared__ int PV[TXV];
  int g = blockIdx.x;           // b(2) x pvt(64) x xt(8)
  int b = g >> 9, pvt = (g >> 3) & 63, xt = g & 7;
  int pv0 = pvt * TXV;
  int xyz0 = xt * 64;
  int t = threadIdx.x;
  if (t < TXV) PV[t] = perm[pv0 + t];
  __syncthreads();
  int lane = t & 63, pg = t >> 6;   // 8 pair-groups
#pragma unroll
  for (int st = 0; st < 48; ++st) {
    int pair = st * 8 + pg;         // 0..383
    int vloc = pair >> 5, f = pair & 31;
    float val = x[((size_t)(b * FINC + f) * V + PV[vloc]) * XYZ + xyz0 + lane];
    TL[pair][lane] = f2bf(val);
  }
  __syncthreads();
  int s = t & 7, xyz = t >> 3;
  u32* dst = (u32*)(xT + ((size_t)(b * XYZ + xyz0 + xyz) * V + pv0) * FINC);
#pragma unroll
  for (int it = 0; it < 24; ++it) {
    int i = s + 8 * it;             // u32 index 0..191
    u32 lo = TL[2 * i][xyz], hi = TL[2 * i + 1][xyz];
    dst[i] = lo | (hi << 16);
  }
}

// ---------- kernel 4: fused recursion + MFMA GEMM; software-pipelined gather ----------
__global__ __launch_bounds__(1024, 4) void cheb_main(
    const u16* __restrict__ xT, const int2* __restrict__ ep3,
    const int* __restrict__ perm, const int* __restrict__ wtrip,
    const float* __restrict__ weight, const float* __restrict__ bias,
    u32* __restrict__ stage) {
  __shared__ __align__(16) u16   CUR[V * ROWP];   // 61440 B (T_k)
  __shared__ __align__(16) u16   PRV[V * ROWP];   // 61440 B (T_{k-1})
  __shared__ __align__(16) uint4 WF[5][2][64];    // 10240 B
  __shared__ u16 PRM[V];
  __shared__ int WT[12];

  int g = blockIdx.x;
  int xcd = g & 7;
  int u = g >> 3;
  int phase = u >> 5;
  int xyz = xcd * 32 + (u & 31) + (phase & 1) * 256;
  int b = phase >> 1;
  int slice = b * XYZ + xyz;

  int tid = threadIdx.x;
  int lane = tid & 63;
  int w = tid >> 6;               // wave 0..15
  int l15 = lane & 15, l4 = lane >> 4;
  bool gath = tid < V;            // waves 0..11 gather/own rows

  if (tid < 640) {
    int k = tid >> 7, n = (tid >> 6) & 1, ln = tid & 63;
    int a15 = ln & 15, a4 = ln >> 4;
    u32 pw[4];
#pragma unroll
    for (int p = 0; p < 4; ++p) {
      float w0 = weight[(size_t)(k * FINC + a4 * 8 + 2 * p) * FOUTC + n * 16 + a15];
      float w1 = weight[(size_t)(k * FINC + a4 * 8 + 2 * p + 1) * FOUTC + n * 16 + a15];
      pw[p] = (u32)f2bf(w0) | ((u32)f2bf(w1) << 16);
    }
    WF[k][n][ln] = make_uint4(pw[0], pw[1], pw[2], pw[3]);
  }
  if (tid < 12) WT[tid] = wtrip[tid];
  if (gath) PRM[tid] = (u16)perm[tid];
  float bsv[2] = {bias[l15], bias[16 + l15]};

  // ---- load permuted slice row tid into LDS (CUR only; PRV set in update 0)
  if (gath) {
    const uint4* src = (const uint4*)(xT + (size_t)slice * V * FINC) + tid * 4;
    uint4* dst = (uint4*)(CUR + tid * ROWP);
#pragma unroll
    for (int j = 0; j < 4; ++j) dst[j] = src[j];
  }
  __syncthreads();   // orders all xT reads before aliased stage writes at the end

  int trip = 0;
  if (w < 12) trip = __builtin_amdgcn_readfirstlane(WT[w]);
  const int2* pp = ep3 + tid;

  f32x4 acc[3][2];
#pragma unroll
  for (int a = 0; a < 3; ++a)
#pragma unroll
    for (int n = 0; n < 2; ++n) acc[a][n] = (f32x4){0.f, 0.f, 0.f, 0.f};

  // 16 waves x 48 rows each
  auto gemm_acc = [&](int k) {
    bf16x8 bn0 = *(const bf16x8*)&WF[k][0][lane];
    bf16x8 bn1 = *(const bf16x8*)&WF[k][1][lane];
#pragma unroll
    for (int a = 0; a < 3; ++a) {
      int row = w * 48 + a * 16 + l15;
      bf16x8 af = *(const bf16x8*)(CUR + row * ROWP + l4 * 8);
      acc[a][0] = __builtin_amdgcn_mfma_f32_16x16x32_bf16(af, bn0, acc[a][0], 0, 0, 0);
      acc[a][1] = __builtin_amdgcn_mfma_f32_16x16x32_bf16(af, bn1, acc[a][1], 0, 0, 0);
    }
  };

  // fa2 = (L * CUR)[tid,:] — software-pipelined: issue edge e+1 reads, FMA edge e.
  f32x2 fa2[16];
  auto fma_edge = [&](float fv, uint4 qa, uint4 qb, uint4 qc, uint4 qd) {
    f32x2 fv2 = {fv, fv};
    u32 wq[16] = {qa.x, qa.y, qa.z, qa.w, qb.x, qb.y, qb.z, qb.w,
                  qc.x, qc.y, qc.z, qc.w, qd.x, qd.y, qd.z, qd.w};
#pragma unroll
    for (int p = 0; p < 16; ++p) {
      f32x2 s = {bflo(wq[p]), bfhi_raw(wq[p])};   // raw hi: <=2^-8 rel noise
      fa2[p] += fv2 * s;
    }
  };
  auto gather = [&]() {
#pragma unroll
    for (int j = 0; j < 16; ++j) fa2[j] = (f32x2){0.f, 0.f};
    int trips = (trip + 1) & ~1;                  // even; padded edges have val 0
    int2 r0 = pp[0], r1 = pp[V], r2 = pp[2 * V];  // pair ring (e, e+1, e+2)
    const uint4* s0 = (const uint4*)((const char*)CUR + (u32)r0.x);
    uint4 A0 = s0[0], A1 = s0[1], A2 = s0[2], A3 = s0[3];
    for (int e = 0; e < trips; e += 2) {
      const uint4* s1 = (const uint4*)((const char*)CUR + (u32)r1.x);
      uint4 B0 = s1[0], B1 = s1[1], B2 = s1[2], B3 = s1[3];  // issue edge e+1
      int2 n3 = pp[(e + 3) * V];
      fma_edge(__int_as_float(r0.y), A0, A1, A2, A3);        // consume edge e
      const uint4* s2 = (const uint4*)((const char*)CUR + (u32)r2.x);
      A0 = s2[0]; A1 = s2[1]; A2 = s2[2]; A3 = s2[3];        // issue edge e+2
      int2 n4 = pp[(e + 4) * V];
      fma_edge(__int_as_float(r1.y), B0, B1, B2, B3);        // consume edge e+1
      r0 = r2; r1 = n3; r2 = n4;
    }
  };

  // update: CUR=new T, PRV=old T.  first: T1=fa2; else: T_{k+1}=2*fa2-PRV
  auto do_update = [&](bool first) {
    uint4* cp = (uint4*)(CUR + tid * ROWP);
    uint4* qp = (uint4*)(PRV + tid * ROWP);
    uint4 c[4];
#pragma unroll
    for (int j = 0; j < 4; ++j) c[j] = cp[j];
    u32 npk[16];
    if (first) {
#pragma unroll
      for (int j = 0; j < 16; ++j) npk[j] = cvtpk_bf16(fa2[j][0], fa2[j][1]);
    } else {
      uint4 pv[4];
#pragma unroll
      for (int j = 0; j < 4; ++j) pv[j] = qp[j];
      u32 wp[16] = {pv[0].x, pv[0].y, pv[0].z, pv[0].w, pv[1].x, pv[1].y, pv[1].z, pv[1].w,
                    pv[2].x, pv[2].y, pv[2].z, pv[2].w, pv[3].x, pv[3].y, pv[3].z, pv[3].w};
#pragma unroll
      for (int j = 0; j < 16; ++j) {
        float t0 = 2.f * fa2[j][0] - bflo(wp[j]);
        float t1 = 2.f * fa2[j][1] - bfhi(wp[j]);
        npk[j] = cvtpk_bf16(t0, t1);
      }
    }
#pragma unroll
    for (int j = 0; j < 4; ++j) {
      qp[j] = c[j];                               // PRV = old T
      cp[j] = make_uint4(npk[4 * j], npk[4 * j + 1], npk[4 * j + 2], npk[4 * j + 3]);
    }
  };

  // ---- phases 0..3: gemm(T_k) ∥ gather(L*T_k) → barrier → update → barrier
#pragma unroll
  for (int ph = 0; ph <= 3; ++ph) {
    gemm_acc(ph);
    if (gath) gather();
    __syncthreads();
    if (gath) do_update(ph == 0);
    __syncthreads();
  }

  // ---- phase 4
  gemm_acc(4);

  // ---- epilogue: pack (fout, fout+16) per lane -> bf16 stage[slice][v][l15]
  u32* stg = stage + (size_t)slice * (V * 16);
#pragma unroll
  for (int a = 0; a < 3; ++a) {
#pragma unroll
    for (int r = 0; r < 4; ++r) {
      int vr = PRM[w * 48 + a * 16 + l4 * 4 + r];
      u32 pk = cvtpk_bf16(acc[a][0][r] + bsv[0], acc[a][1][r] + bsv[1]);
      stg[vr * 16 + l15] = pk;
    }
  }
}

// ---------- kernel 5: stage [b][xyz][v][f2] bf16 -> out [b][fout][v][xyz] f32 ----------
#define TO_VT  12
#define TO_PAD 193
__global__ __launch_bounds__(512) void transpose_out(const u32* __restrict__ stage,
                                                     float* __restrict__ out) {
  __shared__ u32 T[64 * TO_PAD];   // 49.4 KB -> 2 blocks/CU
  int g = blockIdx.x;              // b(2) x vt(64) x xt(8)
  int b = g >> 9, vt = (g >> 3) & 63, xt = g & 7;
  int v0 = vt * TO_VT;
  int xyz0 = xt * 64;
  int t = threadIdx.x;
  const u32* base = stage + (size_t)(b * XYZ + xyz0) * (V * 16) + v0 * 16;
#pragma unroll
  for (int i = 0; i < 6; ++i) {
    int idx4 = i * 512 + t;
    int j = idx4 / 48;
    int c4 = idx4 - j * 48;
    uint4 q = *(const uint4*)(base + (size_t)j * (V * 16) + c4 * 4);
    int w0 = c4 * 4;
    T[j * TO_PAD + w0]     = q.x;
    T[j * TO_PAD + w0 + 1] = q.y;
    T[j * TO_PAD + w0 + 2] = q.z;
    T[j * TO_PAD + w0 + 3] = q.w;
  }
  __syncthreads();
  int wv = t >> 6, lane = t & 63;  // wave, lane=xyz
#pragma unroll
  for (int i = 0; i < 48; ++i) {
    int fout = wv * 4 + i / 12;
    int vv = i % 12;
    u32 pk = T[lane * TO_PAD + vv * 16 + (fout & 15)];
    float val = (fout < 16) ? bflo(pk) : bfhi(pk);
    out[((size_t)(b * FOUTC + fout) * V + v0 + vv) * XYZ + xyz0 + lane] = val;
  }
}

extern "C" void kernel_launch(void* const* d_in, const int* in_sizes, int n_in,
                              void* d_out, int out_size, void* d_ws, size_t ws_size,
                              hipStream_t stream) {
  const int*   lap_rows = (const int*)d_in[0];
  const int*   lap_cols = (const int*)d_in[1];
  const float* lap_vals = (const float*)d_in[2];
  const float* x        = (const float*)d_in[3];
  const float* weight   = (const float*)d_in[4];
  const float* bias     = (const float*)d_in[5];
  float* out = (float*)d_out;
  int nnz = in_sizes[0];

  char* ws = (char*)d_ws;
  const size_t XT_BYTES = (size_t)NB * XYZ * V * FINC * sizeof(u16);  // 50,331,648
  const size_t EP_BYTES = (size_t)V * MAXDEG * 8;                     // 196,608
  const size_t E3_BYTES = (size_t)EROWS * V * 8;                      // 221,184
  u16*  xT    = (u16*)ws;                // aliased: bf16 stage [b][xyz][v][f2]
  u32*  stg   = (u32*)ws;
  int2* epair = (int2*)(ws + XT_BYTES);
  int2* ep3   = (int2*)(ws + XT_BYTES + EP_BYTES);
  int*  deg   = (int*)(ws + XT_BYTES + EP_BYTES + E3_BYTES);
  int*  perm  = (int*)(ws + XT_BYTES + EP_BYTES + E3_BYTES + 3072);
  int*  inv_g = (int*)(ws + XT_BYTES + EP_BYTES + E3_BYTES + 6144);
  int*  wtrip = (int*)(ws + XT_BYTES + EP_BYTES + E3_BYTES + 9216);

  hipLaunchKernelGGL(build_ell, dim3(V), dim3(64), 0, stream,
                     lap_rows, lap_cols, lap_vals, nnz, epair, deg);
  hipLaunchKernelGGL(sort_rows, dim3(1), dim3(V), 0, stream,
                     epair, deg, ep3, perm, inv_g, wtrip);
  hipLaunchKernelGGL(transpose_x, dim3(NB * 64 * 8), dim3(512), 0, stream,
                     x, perm, xT);
  hipLaunchKernelGGL(cheb_main, dim3(NB * XYZ), dim3(1024), 0, stream,
                     xT, ep3, perm, wtrip, weight, bias, stg);
  hipLaunchKernelGGL(transpose_out, dim3(NB * 64 * 8), dim3(512), 0, stream,
                     stg, out);
}